// Round 7
// baseline (155.149 us; speedup 1.0000x reference)
//
#include <hip/hip_runtime.h>

// TanhAttention: B=4, L=512, D=256
//   scores[b,i,j] = sum_d tanh(H[b,i,d]+H[b,j,d]) * w[d] + bias
//   alpha = softmax_j(scores); r = alpha @ H
// Outputs concatenated: r (524288 floats) then alpha (1048576 floats).
//
// Math: tanh(x) = 1 - 2/(1+e^{2x}); with E = exp2(K*h), K = 2*log2(e):
//   e^{2(hi+hj)} = Ei*Ej  ->  score_shifted = -2*sum_d w_d * rcp(fma(Ei,Ej,1))
// (softmax shift cancels sum(w)+bias -> bias unused; symmetric -> upper tiles only).
//
// R13-R19 ladder: score 8-wave straight-line (issue-floor ~13us, rcp-dominated);
//   phase-2 8-rows/block (L2 floor ~6.5us); R19 wlds+pin -> 3 blocks/CU (85.2).
// R16 attribution: score+gap = 17.8 => per-dispatch gap ~5us. Both kernels at
//   their floors -> the gap IS the remaining lever.
// R20: single-dispatch fusion via ticket barrier (no coop launch, no dispatch-
//   order assumption). All 2112 blocks: score tile -> release fetch_add(g_ctr).
//   Last 256 finishers (ticket>=1856) acquire-spin to 2112, run phase-2 chunk.
//   Deadlock-free: when ticket 1856 issues, <=255 blocks unfinished, all
//   resident. Globals reset via ack protocol for graph replay. LDS: phase-2
//   squeezed to 32KB (pr[4] two-step reduce, union'd with sc2), outer union
//   with score's 47.7KB -> 47.7KB, 3 blocks/CU kept. Predict 85.2 -> ~80-82.

#define B_ 4
#define L_ 512
#define D_ 256
#define NT16 32         // L_/16
#define NTRI16 528      // 32*33/2 upper-tri 16x16 tiles per batch
#define NTG (B_ * NTRI16)   // 2112 score tiles
#define NCHUNK 256      // phase-2 row-chunks (8 rows each)
#define ST 36           // staging slot stride (dwords): conflict-free, 16B-aligned

typedef float v4f __attribute__((ext_vector_type(4)));

__device__ int g_ctr = 0;   // score-done tickets (reset each launch by protocol)
__device__ int g_ack = 0;   // spinners-passed acks

union BigLds {
    struct {                            // ---- score phase (47.66 KB) ----
        float lds[8][32 * ST];          // 36.9 KB staging (E values)
        float pr[8][16][17];            // 8.7 KB partial scores
        float sc[16][17];               // 1.1 KB mirror transpose
        float wlds[8][32];              // 1 KB per-wave w slices
    } s1;
    union {                             // ---- phase 2 (32 KB) ----
        float sc2[8][L_];               // 16 KB alpha rows (A,B)
        float pr2[4][8][D_];            // 32 KB partial r (C; sc2 dead)
    } s2;
};

__global__ __launch_bounds__(512, 6) void fused_kernel(
    const float* __restrict__ H, const float* __restrict__ w,
    float* __restrict__ rOut, float* __restrict__ aOut)
{
    __shared__ BigLds U;
    __shared__ int ticket;

    const int tid  = threadIdx.x;
    const int wv   = tid >> 6;               // wave 0..7
    const int lane = tid & 63;
    const float L2E = 1.4426950408889634f;

    // ================= score phase (R19 body) =================
    {
        const int blk  = blockIdx.x;         // 0 .. 2111
        const int b    = blk / NTRI16;
        const int t    = blk - b * NTRI16;
        const int u    = NTRI16 - t;
        int n = (int)((__builtin_amdgcn_sqrtf((float)(8 * u + 1)) - 1.0f) * 0.5f);
        while (n * (n + 1) / 2 < u) ++n;     // fp fixup, <=2 iters
        const int ti = NT16 - n;
        const int tj = ti + (t - (NTRI16 - n * (n + 1) / 2));
        const int i0 = ti * 16, j0 = tj * 16;
        const int dq0 = wv * 32;             // this wave's 32-d slice
        const float K = 2.8853900817779268f; // 2*log2(e)
        const float* Hb = H + (size_t)b * L_ * D_;
        const int ig = lane >> 3, jg = lane & 7;
        float* const buf = &U.s1.lds[wv][0];

        // w slice -> this wave's LDS (wave-local)
        if (lane < 32) U.s1.wlds[wv][lane] = w[dq0 + lane];

        // stage 32 rows x 32 d: 256 quads / 64 lanes = 4 each
        float4 hv[4];
        int slot[4], scol[4];
        #pragma unroll
        for (int s = 0; s < 4; ++s) {
            int idx = lane + 64 * s;
            int r = idx >> 3, q = idx & 7;
            int srow = (r < 16) ? (i0 + r) : (j0 + r - 16);
            slot[s] = r;
            scol[s] = 4 * q;
            hv[s] = *(const float4*)(Hb + srow * D_ + dq0 + 4 * q);
        }
        #pragma unroll
        for (int s = 0; s < 4; ++s) {
            v4f ev;
            ev.x = __builtin_amdgcn_exp2f(hv[s].x * K);
            ev.y = __builtin_amdgcn_exp2f(hv[s].y * K);
            ev.z = __builtin_amdgcn_exp2f(hv[s].z * K);
            ev.w = __builtin_amdgcn_exp2f(hv[s].w * K);
            *(v4f*)&buf[slot[s] * ST + scol[s]] = ev;
        }
        __builtin_amdgcn_wave_barrier();     // pin ds_writes before reads (own wave)

        v4f acc[2][2];
        #pragma unroll
        for (int ii = 0; ii < 2; ++ii)
            #pragma unroll
            for (int jj = 0; jj < 2; ++jj) acc[ii][jj] = (v4f){0.f, 0.f, 0.f, 0.f};

        #pragma unroll
        for (int q = 0; q < 8; ++q) {        // 4-d block per step
            v4f wvv = *(const v4f*)&U.s1.wlds[wv][4 * q];  // uniform broadcast
            v4f Ei[2], Ej[2];
            #pragma unroll
            for (int ii = 0; ii < 2; ++ii)
                Ei[ii] = *(const v4f*)&buf[(ii * 8 + ig) * ST + 4 * q];
            #pragma unroll
            for (int jj = 0; jj < 2; ++jj)
                Ej[jj] = *(const v4f*)&buf[(16 + jj * 8 + jg) * ST + 4 * q];
            #pragma unroll
            for (int ii = 0; ii < 2; ++ii)
                #pragma unroll
                for (int jj = 0; jj < 2; ++jj) {
                    v4f den = Ei[ii] * Ej[jj] + 1.0f;
                    v4f rr;
                    rr.x = __builtin_amdgcn_rcpf(den.x);
                    rr.y = __builtin_amdgcn_rcpf(den.y);
                    rr.z = __builtin_amdgcn_rcpf(den.z);
                    rr.w = __builtin_amdgcn_rcpf(den.w);
                    acc[ii][jj] += wvv * rr;
                }
        }

        #pragma unroll
        for (int ii = 0; ii < 2; ++ii)
            #pragma unroll
            for (int jj = 0; jj < 2; ++jj) {
                v4f a = acc[ii][jj];
                U.s1.pr[wv][ig + 8 * ii][jg + 8 * jj] = a.x + a.y + a.z + a.w;
            }
        __syncthreads();

        float val = 0.0f;
        const int row = (tid >> 4) & 15, col = tid & 15;
        if (tid < 256) {
            #pragma unroll
            for (int k = 0; k < 8; ++k) val += U.s1.pr[k][row][col];
            val *= -2.0f;                    // shifted score
            aOut[((size_t)b * L_ + i0 + row) * L_ + j0 + col] = val;
        }
        if (ti != tj) {                      // mirror via LDS transpose
            if (tid < 256) U.s1.sc[row][col] = val;
            __syncthreads();
            if (tid < 256)
                aOut[((size_t)b * L_ + j0 + row) * L_ + i0 + col] = U.s1.sc[col][row];
        }
    }

    // ================= ticket barrier =================
    __syncthreads();                         // all waves' stores drained (vmcnt0 before barrier)
    if (tid == 0) {
        ticket = __hip_atomic_fetch_add(&g_ctr, 1, __ATOMIC_RELEASE,
                                        __HIP_MEMORY_SCOPE_AGENT);
    }
    __syncthreads();
    const int tk = ticket;
    if (tk < NTG - NCHUNK) return;           // not a phase-2 block

    if (tid == 0) {
        while (__hip_atomic_load(&g_ctr, __ATOMIC_ACQUIRE,
                                 __HIP_MEMORY_SCOPE_AGENT) < NTG)
            __builtin_amdgcn_s_sleep(2);
        __hip_atomic_fetch_add(&g_ack, 1, __ATOMIC_RELAXED,
                               __HIP_MEMORY_SCOPE_AGENT);
    }
    __syncthreads();                         // block released; caches invalidated

    // ================= phase 2 (R17 body, 32KB LDS) =================
    const int chunk = tk - (NTG - NCHUNK);   // 0..255
    const int b2    = chunk >> 6;
    const int i0    = (chunk & 63) * 8;
    const float* Hb = H + (size_t)b2 * L_ * D_;

    // ---- A: softmax, wave wv handles row wv ----
    {
        const int row = wv;
        float* aRow = aOut + ((size_t)b2 * L_ + i0 + row) * L_;
        float v[8];
        float m = -1e30f;
        #pragma unroll
        for (int k = 0; k < 8; ++k) {
            v[k] = aRow[lane + 64 * k];
            m = fmaxf(m, v[k]);
        }
        #pragma unroll
        for (int off = 1; off < 64; off <<= 1)
            m = fmaxf(m, __shfl_xor(m, off, 64));
        float s = 0.0f;
        #pragma unroll
        for (int k = 0; k < 8; ++k) {
            v[k] = __builtin_amdgcn_exp2f((v[k] - m) * L2E);
            s += v[k];
        }
        #pragma unroll
        for (int off = 1; off < 64; off <<= 1)
            s += __shfl_xor(s, off, 64);
        const float inv = __builtin_amdgcn_rcpf(s);
        #pragma unroll
        for (int k = 0; k < 8; ++k) {
            float a = v[k] * inv;
            U.s2.sc2[row][lane + 64 * k] = a;
            aRow[lane + 64 * k] = a;         // overwrite scores with alpha
        }
    }
    __syncthreads();

    // ---- B: r-phase, wave-cooperative over j (64 j per wave), 8 rows ----
    const int jbase = 64 * wv;
    v4f racc[8];
    #pragma unroll
    for (int r = 0; r < 8; ++r) racc[r] = (v4f){0.f, 0.f, 0.f, 0.f};
    const v4f* Hb4 = (const v4f*)Hb;         // [512][64]

    #pragma unroll 2
    for (int js = 0; js < 64; js += 4) {
        v4f h[4];
        #pragma unroll
        for (int q = 0; q < 4; ++q)
            h[q] = Hb4[(size_t)(jbase + js + q) * (D_ / 4) + lane];
        #pragma unroll
        for (int r = 0; r < 8; ++r) {
            v4f av = *(const v4f*)&U.s2.sc2[r][jbase + js];
            #pragma unroll
            for (int q = 0; q < 4; ++q)
                racc[r] += av[q] * h[q];
        }
    }
    __syncthreads();                 // all sc2 reads done before pr2 (aliased!) writes

    // ---- C: two-step reduce (pr2[4] = 32KB, aliases sc2) ----
    if (wv >= 4) {
        #pragma unroll
        for (int r = 0; r < 8; ++r)
            *(v4f*)&U.s2.pr2[wv - 4][r][4 * lane] = racc[r];
    }
    __syncthreads();
    if (wv < 4) {
        #pragma unroll
        for (int r = 0; r < 8; ++r) {
            v4f p = *(const v4f*)&U.s2.pr2[wv][r][4 * lane];
            *(v4f*)&U.s2.pr2[wv][r][4 * lane] = p + racc[r];
        }
    }
    __syncthreads();
    {
        const int fq  = tid & 63;        // float4 index in D
        const int row = tid >> 6;        // 0..7
        v4f s = *(const v4f*)&U.s2.pr2[0][row][4 * fq];
        #pragma unroll
        for (int k = 1; k < 4; ++k)
            s += *(const v4f*)&U.s2.pr2[k][row][4 * fq];
        *(v4f*)&rOut[((size_t)b2 * L_ + i0 + row) * D_ + 4 * fq] = s;
    }

    // ---- reset protocol: designated resetter restores globals to 0 ----
    if (tk == NTG - 1 && tid == 0) {
        while (__hip_atomic_load(&g_ack, __ATOMIC_RELAXED,
                                 __HIP_MEMORY_SCOPE_AGENT) < NCHUNK)
            __builtin_amdgcn_s_sleep(2);
        __hip_atomic_store(&g_ack, 0, __ATOMIC_RELAXED, __HIP_MEMORY_SCOPE_AGENT);
        __hip_atomic_store(&g_ctr, 0, __ATOMIC_RELEASE, __HIP_MEMORY_SCOPE_AGENT);
    }
}

extern "C" void kernel_launch(void* const* d_in, const int* in_sizes, int n_in,
                              void* d_out, int out_size, void* d_ws, size_t ws_size,
                              hipStream_t stream) {
    const float* H = (const float*)d_in[0];
    const float* w = (const float*)d_in[1];
    // d_in[2] (bias) unused: softmax shift-invariance cancels it.
    float* rOut = (float*)d_out;
    float* aOut = rOut + (size_t)B_ * L_ * D_;   // alpha region doubles as score scratch

    fused_kernel<<<dim3(NTG), 512, 0, stream>>>(H, w, rOut, aOut);
}

// Round 8
// 84.907 us; speedup vs baseline: 1.8273x; 1.8273x over previous
//
#include <hip/hip_runtime.h>

// TanhAttention: B=4, L=512, D=256
//   scores[b,i,j] = sum_d tanh(H[b,i,d]+H[b,j,d]) * w[d] + bias
//   alpha = softmax_j(scores); r = alpha @ H
// Outputs concatenated: r (524288 floats) then alpha (1048576 floats).
//
// Math: tanh(x) = 1 - 2/(1+e^{2x}); with E = exp2(K*h), K = 2*log2(e):
//   e^{2(hi+hj)} = Ei*Ej  ->  score_shifted = -2*sum_d w_d * rcp(fma(Ei,Ej,1))
// (softmax shift cancels sum(w)+bias -> bias unused; symmetric -> upper tiles only).
//
// Ladder: R13 8-wave score; R14 T2 waves x2 -> 0 (BW-bound); R15 w->SGPR -> +1.9
//   (reverted); R16 attribution: score+gap=17.8, gap~3-5/dispatch; R17 T2
//   rows/block 8 -> -1.6 (L2 floor); R18 persistent 512-block -> +5.2 (cut
//   occupancy 3->2 blocks/CU; TLP-sensitive); R19 wlds + pin -> -0.8 (85.2, 3
//   blocks/CU); R20 ticket-barrier fusion -> +70us CATASTROPHE: agent-scope
//   release/acquire on non-coherent per-XCD L2s (writeback+invalidate per
//   block/poll) >> the 5us gap it saved. Fusion dead; gaps irreducible here.
// R21: revert to R19 + epilogue cleanup: threads 256-511 compute the mirror
//   element directly from pr (transposed read, 17-stride ~2-way = free) ->
//   drops sc buffer, 2 syncthreads, and the ti!=tj branch (diagonal double-
//   writes are bit-identical: same staged E slots, commutative mul, same
//   reduction order). Score floor: 134M rcp (trans) + 268M fma -- algorithmic
//   minimum; T2 at L2 floor; remaining budget = harness fill (40.5) + gaps.

#define B_ 4
#define L_ 512
#define D_ 256
#define NT16 32         // L_/16
#define NTRI16 528      // 32*33/2 upper-tri 16x16 tiles per batch
#define ST 36           // staging slot stride (dwords): quad-padded, 16B-aligned

typedef float v4f __attribute__((ext_vector_type(4)));

__global__ __launch_bounds__(512, 6) void score_kernel(
    const float* __restrict__ H, const float* __restrict__ w,
    float* __restrict__ sOut)
{
    __shared__ __align__(16) float lds[8][32 * ST];   // 36.9 KB staging (E values)
    __shared__ float pr[8][16][17];                   // 8.7 KB partial scores
    __shared__ __align__(16) float wlds[8][32];       // 1 KB per-wave w slices

    const int tid  = threadIdx.x;
    const int wv   = tid >> 6;               // D-slice index 0..7
    const int lane = tid & 63;
    const int blk  = blockIdx.x;             // 0 .. 2111 (one block per (b,tile))
    const int b    = blk / NTRI16;
    const int t    = blk - b * NTRI16;
    // closed-form upper-tri index: n = 32-ti solves n(n+1)/2 >= u, u = 528-t
    const int u  = NTRI16 - t;
    int n = (int)((__builtin_amdgcn_sqrtf((float)(8 * u + 1)) - 1.0f) * 0.5f);
    while (n * (n + 1) / 2 < u) ++n;         // fp fixup, <=2 iters
    const int ti = NT16 - n;
    const int tj = ti + (t - (NTRI16 - n * (n + 1) / 2));
    const int i0 = ti * 16, j0 = tj * 16;
    const int dq0 = wv * 32;                 // this wave's 32-d slice
    const float K = 2.8853900817779268f;     // 2*log2(e)
    const float* Hb = H + (size_t)b * L_ * D_;

    const int ig = lane >> 3, jg = lane & 7; // i = i0+ig+8*ii, j = j0+jg+8*jj

    float* const buf = &lds[wv][0];

    // w slice -> this wave's LDS (wave-local: wave_barrier suffices)
    if (lane < 32) wlds[wv][lane] = w[dq0 + lane];

    // ---- stage this wave's 32 rows x 32 d: 256 quads / 64 lanes = 4 each ----
    float4 hv[4];
    int slot[4], scol[4];
    #pragma unroll
    for (int s = 0; s < 4; ++s) {
        int idx = lane + 64 * s;
        int r = idx >> 3, q = idx & 7;
        int srow = (r < 16) ? (i0 + r) : (j0 + r - 16);
        slot[s] = r;
        scol[s] = 4 * q;
        hv[s] = *(const float4*)(Hb + srow * D_ + dq0 + 4 * q);   // batched loads
    }
    #pragma unroll
    for (int s = 0; s < 4; ++s) {
        v4f ev;
        ev.x = __builtin_amdgcn_exp2f(hv[s].x * K);
        ev.y = __builtin_amdgcn_exp2f(hv[s].y * K);
        ev.z = __builtin_amdgcn_exp2f(hv[s].z * K);
        ev.w = __builtin_amdgcn_exp2f(hv[s].w * K);
        *(v4f*)&buf[slot[s] * ST + scol[s]] = ev;
    }

    __builtin_amdgcn_wave_barrier();         // pin ds_writes before reads (own wave only)

    v4f acc[2][2];
    #pragma unroll
    for (int ii = 0; ii < 2; ++ii)
        #pragma unroll
        for (int jj = 0; jj < 2; ++jj) acc[ii][jj] = (v4f){0.f, 0.f, 0.f, 0.f};

    #pragma unroll
    for (int q = 0; q < 8; ++q) {            // 4-d block per step
        v4f wvv = *(const v4f*)&wlds[wv][4 * q];   // uniform-address broadcast read
        v4f Ei[2], Ej[2];
        #pragma unroll
        for (int ii = 0; ii < 2; ++ii)       // slots ii*8+ig: all 32 banks once
            Ei[ii] = *(const v4f*)&buf[(ii * 8 + ig) * ST + 4 * q];
        #pragma unroll
        for (int jj = 0; jj < 2; ++jj)
            Ej[jj] = *(const v4f*)&buf[(16 + jj * 8 + jg) * ST + 4 * q];
        #pragma unroll
        for (int ii = 0; ii < 2; ++ii)
            #pragma unroll
            for (int jj = 0; jj < 2; ++jj) {
                v4f den = Ei[ii] * Ej[jj] + 1.0f;
                v4f rr;
                rr.x = __builtin_amdgcn_rcpf(den.x);
                rr.y = __builtin_amdgcn_rcpf(den.y);
                rr.z = __builtin_amdgcn_rcpf(den.z);
                rr.w = __builtin_amdgcn_rcpf(den.w);
                acc[ii][jj] += wvv * rr;
            }
    }

    // ---- partials to LDS ----
    #pragma unroll
    for (int ii = 0; ii < 2; ++ii)
        #pragma unroll
        for (int jj = 0; jj < 2; ++jj) {
            v4f a = acc[ii][jj];
            pr[wv][ig + 8 * ii][jg + 8 * jj] = a.x + a.y + a.z + a.w;
        }
    __syncthreads();

    // ---- combine: all 512 threads; lower half = upper tile, upper half = mirror.
    // Diagonal tiles: both halves write the same location with bit-identical
    // values (same staged E slots, commutative mul, same k/q reduction order).
    {
        const int row = (tid >> 4) & 15, col = tid & 15;
        if (tid < 256) {
            float val = 0.0f;
            #pragma unroll
            for (int k = 0; k < 8; ++k) val += pr[k][row][col];
            val *= -2.0f;                    // shifted score
            sOut[((size_t)b * L_ + i0 + row) * L_ + j0 + col] = val;
        } else {
            float val = 0.0f;                // mirror: tile[col][row] at (j0+row, i0+col)
            #pragma unroll
            for (int k = 0; k < 8; ++k) val += pr[k][col][row];
            val *= -2.0f;
            sOut[((size_t)b * L_ + j0 + row) * L_ + i0 + col] = val;
        }
    }
}

// Phase 2 (R17, near L2-BW floor): 256 blocks x 512 thr (8 waves); 8 rows/block.
// A: softmax, wave w owns row w. B: r-phase, wave w owns j in [64w,64w+64),
// racc[8]; H[b] once per block (128MB L2 total). C: union'd pr reduce.
union SMem {
    float sc[8][L_];          // 16 KB (phases A,B)
    float pr[8][8][D_];       // 64 KB (phase C)
};

__global__ __launch_bounds__(512) void softmax_r_kernel(
    const float* __restrict__ H, float* __restrict__ rOut, float* __restrict__ aOut)
{
    __shared__ __align__(16) SMem u;

    const int tid  = threadIdx.x;
    const int blk  = blockIdx.x;     // 0..255
    const int b    = blk >> 6;
    const int i0   = (blk & 63) * 8;
    const int wv   = tid >> 6;       // wave 0..7
    const int lane = tid & 63;
    const float* Hb = H + (size_t)b * L_ * D_;
    const float L2E = 1.4426950408889634f;

    // ---- A: softmax, wave wv handles row wv ----
    {
        const int row = wv;
        float* aRow = aOut + ((size_t)b * L_ + i0 + row) * L_;
        float v[8];
        float m = -1e30f;
        #pragma unroll
        for (int k = 0; k < 8; ++k) {
            v[k] = aRow[lane + 64 * k];      // coalesced score reads (L2/L3-hot)
            m = fmaxf(m, v[k]);
        }
        #pragma unroll
        for (int off = 1; off < 64; off <<= 1)
            m = fmaxf(m, __shfl_xor(m, off, 64));
        float s = 0.0f;
        #pragma unroll
        for (int k = 0; k < 8; ++k) {
            v[k] = __builtin_amdgcn_exp2f((v[k] - m) * L2E);
            s += v[k];
        }
        #pragma unroll
        for (int off = 1; off < 64; off <<= 1)
            s += __shfl_xor(s, off, 64);
        const float inv = __builtin_amdgcn_rcpf(s);
        #pragma unroll
        for (int k = 0; k < 8; ++k) {
            float a = v[k] * inv;
            u.sc[row][lane + 64 * k] = a;
            aRow[lane + 64 * k] = a;         // overwrite scores with alpha in place
        }
    }
    __syncthreads();

    // ---- B: r-phase, wave-cooperative over j (64 j per wave), 8 rows ----
    const int jbase = 64 * wv;
    v4f racc[8];
    #pragma unroll
    for (int r = 0; r < 8; ++r) racc[r] = (v4f){0.f, 0.f, 0.f, 0.f};
    const v4f* Hb4 = (const v4f*)Hb;         // [512][64]

    #pragma unroll 2
    for (int js = 0; js < 64; js += 4) {
        v4f h[4];
        #pragma unroll
        for (int q = 0; q < 4; ++q)
            h[q] = Hb4[(size_t)(jbase + js + q) * (D_ / 4) + lane];
        #pragma unroll
        for (int r = 0; r < 8; ++r) {
            v4f av = *(const v4f*)&u.sc[r][jbase + js];   // b128 uniform broadcast
            #pragma unroll
            for (int q = 0; q < 4; ++q)
                racc[r] += av[q] * h[q];
        }
    }
    __syncthreads();                 // all sc reads done before pr overwrites it

    #pragma unroll
    for (int r = 0; r < 8; ++r)
        *(v4f*)&u.pr[wv][r][4 * lane] = racc[r];
    __syncthreads();

    // ---- C: reduce 8 wave-partials, write r (all 512 threads) ----
    {
        const int fq  = tid & 63;        // float4 index in D
        const int row = tid >> 6;        // 0..7
        v4f s = *(const v4f*)&u.pr[0][row][4 * fq];
        #pragma unroll
        for (int k = 1; k < 8; ++k)
            s += *(const v4f*)&u.pr[k][row][4 * fq];
        *(v4f*)&rOut[((size_t)b * L_ + i0 + row) * D_ + 4 * fq] = s;
    }
}

extern "C" void kernel_launch(void* const* d_in, const int* in_sizes, int n_in,
                              void* d_out, int out_size, void* d_ws, size_t ws_size,
                              hipStream_t stream) {
    const float* H = (const float*)d_in[0];
    const float* w = (const float*)d_in[1];
    // d_in[2] (bias) unused: softmax shift-invariance cancels it.
    float* rOut = (float*)d_out;
    float* aOut = rOut + (size_t)B_ * L_ * D_;   // alpha region doubles as score scratch

    score_kernel<<<dim3(B_ * NTRI16), 512, 0, stream>>>(H, w, aOut);
    softmax_r_kernel<<<dim3(B_ * (L_ / 8)), 512, 0, stream>>>(H, rOut, aOut);
}